// Round 9
// baseline (196.755 us; speedup 1.0000x reference)
//
#include <hip/hip_runtime.h>

typedef __bf16 bf16_t;
typedef __bf16 bf16x8 __attribute__((ext_vector_type(8)));
typedef __bf16 bf16x4 __attribute__((ext_vector_type(4)));
typedef float f32x4 __attribute__((ext_vector_type(4)));

#define M_DIM 4096
#define N_DIM 4096   // 2 * OUT_FEATURES
#define K_DIM 4096   // 2 * IN_FEATURES
#define OUTF 2048
#define INF 2048
#define LDK 4096
#define NT 64        // K-tiles of 64

// ---------------------------------------------------------------------------
// Pack kernel: build bf16 A = [x_re | x_im]  (4096 x 4096)
//              and  bf16 B = [[w_re, -w_im]; [w_im, w_re]] (4096 x 4096)
// ---------------------------------------------------------------------------
__global__ __launch_bounds__(256) void pack_ab(
    const float* __restrict__ xre, const float* __restrict__ xim,
    const float* __restrict__ wre, const float* __restrict__ wim,
    bf16_t* __restrict__ Abf, bf16_t* __restrict__ Bbf)
{
  size_t gid = (size_t)blockIdx.x * 256 + threadIdx.x;
  size_t e8  = gid * 8;
  const size_t MAT = (size_t)4096 * 4096;
  bool isB = e8 >= MAT;
  size_t e = isB ? (e8 - MAT) : e8;
  int row = (int)(e >> 12);
  int k   = (int)(e & 4095);

  const float* src;
  float s = 1.0f;
  if (!isB) {
    src = (k < INF) ? (xre + (size_t)row * INF + k)
                    : (xim + (size_t)row * INF + (k - INF));
  } else {
    if (row < OUTF) {
      if (k < INF) { src = wre + (size_t)row * INF + k; }
      else         { src = wim + (size_t)row * INF + (k - INF); s = -1.0f; }
    } else {
      int o = row - OUTF;
      src = (k < INF) ? (wim + (size_t)o * INF + k)
                      : (wre + (size_t)o * INF + (k - INF));
    }
  }
  const float4* p = reinterpret_cast<const float4*>(src);
  float4 f0 = p[0];
  float4 f1 = p[1];
  bf16x8 v;
  v[0] = (bf16_t)(f0.x * s); v[1] = (bf16_t)(f0.y * s);
  v[2] = (bf16_t)(f0.z * s); v[3] = (bf16_t)(f0.w * s);
  v[4] = (bf16_t)(f1.x * s); v[5] = (bf16_t)(f1.y * s);
  v[6] = (bf16_t)(f1.z * s); v[7] = (bf16_t)(f1.w * s);
  bf16_t* dst = (isB ? Bbf : Abf) + e;
  *reinterpret_cast<bf16x8*>(dst) = v;
}

// ---------------------------------------------------------------------------
__device__ __forceinline__ void gld_lds16(const void* g, void* l) {
  __builtin_amdgcn_global_load_lds(
      (const __attribute__((address_space(1))) void*)g,
      (__attribute__((address_space(3))) void*)l,
      16, 0, 0);
}

// ---------------------------------------------------------------------------
// 256x256 GEMM, B-direct-from-global (R9).
//   Diagnosis R3-R8: LDS pipe (A+B reads 2304cyc + writes 512 = 2816) >
//   MFMA (2483) -> LDS-bound; schedule changes were null. Fix: B-fragments
//   load straight from global into registers (coalesced 16B/lane, L2-served:
//   XCD swizzle flipped so same-XCD blocks share bn -> 2 B-panels = 4 MiB =
//   one L2). LDS now A-only: 128 reads*12 + 250 = 1786 < 2483 -> MFMA-bound.
//   LDS 64 KiB (2 x 32 KiB dbuf), ONE barrier/tile.
//   Quadrant order QA(0,0) QB(1,0) QC(1,1) QD(0,1): b0 refilled (t+1) after
//   QB, b1 after QD -> ~2 phases of latency cover; compiler's exact per-use
//   vmcnt guards b-frags. Manual vmcnt(8) at boundary drains the 4 A-stage
//   gld_lds while 8 B-loads stay in flight (issue order pinned by SB()).
//   A swizzle unchanged (R3-verified conflicts==0):
//     phys_kbyte = logical_kbyte ^ ((row&3)<<4) ^ (((row>>2)&1)<<6)
// ---------------------------------------------------------------------------

template<int QM, int QN>
__device__ __forceinline__ void mfma_quad(f32x4 (&acc)[8][4],
                                          const bf16x8 (&aF)[4][2],
                                          const bf16x8 (&bF)[2][2]) {
  __builtin_amdgcn_s_setprio(1);
#pragma unroll
  for (int m = 0; m < 4; ++m)
#pragma unroll
    for (int n = 0; n < 2; ++n) {
      f32x4 v = acc[QM * 4 + m][QN * 2 + n];
      v = __builtin_amdgcn_mfma_f32_16x16x32_bf16(aF[m][0], bF[n][0], v, 0, 0, 0);
      v = __builtin_amdgcn_mfma_f32_16x16x32_bf16(aF[m][1], bF[n][1], v, 0, 0, 0);
      acc[QM * 4 + m][QN * 2 + n] = v;
    }
  __builtin_amdgcn_s_setprio(0);
}

__global__ __launch_bounds__(512, 2) void gemm256_bd(
    const bf16_t* __restrict__ A, const bf16_t* __restrict__ B,
    float* __restrict__ out)
{
  // LDS: A only. buf c at c*32768 B; half h (rows h*128..+127) at h*16384;
  // row stride 128 B.
  __shared__ alignas(16) bf16_t lds[2 * 16384];
  char* Lb = (char*)lds;

  const int tid  = threadIdx.x;
  const int lane = tid & 63;
  const int wid  = tid >> 6;
  const int wm   = wid >> 2;   // 0..1  -> rows wm*128..+127 (A-half wm)
  const int wn   = wid & 3;    // 0..3  -> cols wn*64..+63
  const int lr   = lane & 15;
  const int kg   = (lane >> 4) * 16;                         // logical k-byte
  const int xm   = ((lr & 3) << 4) | (((lr >> 2) & 1) << 6); // row-XOR mask

  // XCD swizzle, flipped so same-XCD blocks SHARE bn (B L2-residency):
  // chunk of 32 consecutive swz = one XCD = 16 bm x 2 bn.
  int bid = blockIdx.x;
  int swz = (bid & 7) * 32 + (bid >> 3);   // 256 blocks % 8 == 0
  const int xcd = swz >> 5;                // 0..7
  const int cI  = swz & 31;
  const int bm  = cI & 15;                 // 0..15
  const int bn  = xcd * 2 + (cI >> 4);     // 0..15 (bijective)

  // A staging source precompute (swizzle involution), unchanged from R8:
  int rS[2], kS[2];
#pragma unroll
  for (int j = 0; j < 2; ++j) {
    int P   = j * 8192 + tid * 16;
    int row = P >> 7;
    int p   = P & 127;
    int L   = p ^ ((row & 3) << 4) ^ (((row >> 2) & 1) << 6);
    rS[j] = row;
    kS[j] = L >> 1;
  }
  const bf16_t* As0 = A + (size_t)(bm * 256 + rS[0]) * LDK + kS[0];
  const bf16_t* As1 = A + (size_t)(bm * 256 + rS[1]) * LDK + kS[1];
  const int dst16 = tid * 16;

  // B fragment base pointers (per-lane, logical/unswizzled): frag (qn,n):
  // col = bn*256 + wn*64 + qn*32 + n*16 + lr ; k-elem base (lane>>4)*8.
  const bf16_t* bp[2][2];
#pragma unroll
  for (int qn = 0; qn < 2; ++qn)
#pragma unroll
    for (int n = 0; n < 2; ++n)
      bp[qn][n] = B + (size_t)(bn * 256 + wn * 64 + qn * 32 + n * 16 + lr) * LDK
                    + (lane >> 4) * 8;

#define STAGE_A(t, h, c) do {                                                  \
    gld_lds16(As0 + (size_t)(h) * 128 * LDK + (t) * 64,                        \
              Lb + (c) * 32768 + (h) * 16384 + dst16);                         \
    gld_lds16(As1 + (size_t)(h) * 128 * LDK + (t) * 64,                        \
              Lb + (c) * 32768 + (h) * 16384 + 8192 + dst16);                  \
  } while (0)
#define RD_A(c, qm, m, ks)                                                     \
  (*(const bf16x8*)(Lb + (c) * 32768 + wm * 16384 +                            \
                    ((qm) * 64 + (m) * 16 + lr) * 128 +                        \
                    ((((ks) * 64) | kg) ^ xm)))
#define LDB(qn, n, ks, t)                                                      \
  (*(const bf16x8*)(bp[qn][n] + (size_t)(t) * 64 + (ks) * 32))
#define BAR()   __builtin_amdgcn_s_barrier()
#define SB()    __builtin_amdgcn_sched_barrier(0)

  f32x4 acc[8][4];
#pragma unroll
  for (int i = 0; i < 8; ++i)
#pragma unroll
    for (int j = 0; j < 4; ++j)
      acc[i][j] = (f32x4){0.f, 0.f, 0.f, 0.f};

  bf16x8 b0[2][2], b1[2][2];

  // Prologue: A(0) -> buf0 (4 gld_lds); B(0) frags -> regs (8 loads).
  // vmcnt(8): A drained (8 B-loads in flight; compiler waits before use).
  STAGE_A(0, 0, 0); STAGE_A(0, 1, 0);
  SB();
#pragma unroll
  for (int n = 0; n < 2; ++n)
#pragma unroll
    for (int ks = 0; ks < 2; ++ks) {
      b0[n][ks] = LDB(0, n, ks, 0);
      b1[n][ks] = LDB(1, n, ks, 0);
    }
  asm volatile("s_waitcnt vmcnt(8)" ::: "memory");
  BAR(); SB();

  for (int t = 0; t < NT; ++t) {
    const int c = t & 1;
    bf16x8 a0[4][2], a1[4][2];

    // R1: all 16 A ds_reads + stage A(t+1,h0) + QA. (compiler lgkm-counts)
#pragma unroll
    for (int m = 0; m < 4; ++m) {
      a0[m][0] = RD_A(c, 0, m, 0);
      a0[m][1] = RD_A(c, 0, m, 1);
    }
#pragma unroll
    for (int m = 0; m < 4; ++m) {
      a1[m][0] = RD_A(c, 1, m, 0);
      a1[m][1] = RD_A(c, 1, m, 1);
    }
    if (t + 1 < NT) STAGE_A(t + 1, 0, c ^ 1);
    mfma_quad<0, 0>(acc, a0, b0);     // QA: a0 x b0
    SB();

    // R2: stage A(t+1,h1) + QB (b0's last use).
    if (t + 1 < NT) STAGE_A(t + 1, 1, c ^ 1);
    mfma_quad<1, 0>(acc, a1, b0);     // QB: a1 x b0
    SB();

    // R3: refill b0 <- tile t+1 (drains under QC/QD + next QA) + QC.
    if (t + 1 < NT) {
#pragma unroll
      for (int n = 0; n < 2; ++n)
#pragma unroll
        for (int ks = 0; ks < 2; ++ks)
          b0[n][ks] = LDB(0, n, ks, t + 1);
    }
    mfma_quad<1, 1>(acc, a1, b1);     // QC: a1 x b1
    SB();

    // R4: QD (b1's last use), refill b1 <- t+1, boundary.
    mfma_quad<0, 1>(acc, a0, b1);     // QD: a0 x b1
    if (t + 1 < NT) {
#pragma unroll
      for (int n = 0; n < 2; ++n)
#pragma unroll
        for (int ks = 0; ks < 2; ++ks)
          b1[n][ks] = LDB(1, n, ks, t + 1);
      // FIFO: [Ast h0(2), Ast h1(2), b0(4), b1(4)] -> vmcnt(8) drains A
      // stages only; 8 B-loads cross the barrier in flight.
      asm volatile("s_waitcnt vmcnt(8)" ::: "memory");
    }
    BAR(); SB();
  }

  // Epilogue: C/D layout col=lane&15, row=(lane>>4)*4+j (verified m89/m91)
  const size_t imOff = (size_t)M_DIM * OUTF;
  const int fq = (lane >> 4) * 4;
  const bool isIm = (bn * 256) >= OUTF;          // bn>=8 -> imaginary half
  float* obase = out + (isIm ? imOff : 0);
  const int colBase = bn * 256 - (isIm ? OUTF : 0) + wn * 64;
#pragma unroll
  for (int ar = 0; ar < 8; ++ar) {
    int gr = bm * 256 + wm * 128 + ar * 16 + fq;
#pragma unroll
    for (int cc = 0; cc < 4; ++cc) {
      int gc = colBase + cc * 16 + lr;
#pragma unroll
      for (int j = 0; j < 4; ++j)
        obase[(size_t)(gr + j) * OUTF + gc] = acc[ar][cc][j];
    }
  }
#undef STAGE_A
#undef RD_A
#undef LDB
#undef BAR
#undef SB
}

// ---------------------------------------------------------------------------
// Fallback: fused fp32->bf16 conversion + GEMM (no workspace needed).
// ---------------------------------------------------------------------------
__global__ __launch_bounds__(256) void gemm_fused(
    const float* __restrict__ xre, const float* __restrict__ xim,
    const float* __restrict__ wre, const float* __restrict__ wim,
    float* __restrict__ out)
{
  __shared__ alignas(16) bf16_t As[128 * 40];
  __shared__ alignas(16) bf16_t Bs[128 * 40];

  int tid = threadIdx.x;
  int bid = blockIdx.x;
  int swz = (bid & 7) * 128 + (bid >> 3);
  int bm = swz >> 5;
  int bn = swz & 31;

  int lane = tid & 63;
  int w    = tid >> 6;
  int wm   = (w >> 1) * 64;
  int wn   = (w & 1) * 64;
  int lr   = lane & 15;
  int lk   = (lane >> 4) * 8;

  f32x4 acc[4][4];
#pragma unroll
  for (int m = 0; m < 4; ++m)
#pragma unroll
    for (int n = 0; n < 4; ++n)
      acc[m][n] = (f32x4){0.f, 0.f, 0.f, 0.f};

  int srow = tid >> 3;
  int scol = (tid & 7) * 4;

  bool nIm  = (bn * 128) >= OUTF;
  int nbase = nIm ? (bn * 128 - OUTF) : (bn * 128);

  for (int kt = 0; kt < K_DIM / 32; ++kt) {
    int k0 = kt * 32;
    bool kHi = (k0 >= INF);
    int kk = kHi ? (k0 - INF) : k0;

    const float* Asrc = (kHi ? xim : xre) + (size_t)(bm * 128) * INF + kk;
    const float* Bsrc;
    float s = 1.0f;
    if (!nIm) { if (!kHi) { Bsrc = wre; } else { Bsrc = wim; s = -1.0f; } }
    else      { Bsrc = kHi ? wre : wim; }
    Bsrc += (size_t)nbase * INF + kk;

    float4 av[4], bv[4];
#pragma unroll
    for (int i = 0; i < 4; ++i) {
      av[i] = *reinterpret_cast<const float4*>(Asrc + (size_t)(srow + i * 32) * INF + scol);
      bv[i] = *reinterpret_cast<const float4*>(Bsrc + (size_t)(srow + i * 32) * INF + scol);
    }
    __syncthreads();
#pragma unroll
    for (int i = 0; i < 4; ++i) {
      bf16x4 a4, b4;
      a4[0] = (bf16_t)av[i].x; a4[1] = (bf16_t)av[i].y;
      a4[2] = (bf16_t)av[i].z; a4[3] = (bf16_t)av[i].w;
      b4[0] = (bf16_t)(bv[i].x * s); b4[1] = (bf16_t)(bv[i].y * s);
      b4[2] = (bf16_t)(bv[i].z * s); b4[3] = (bf16_t)(bv[i].w * s);
      *reinterpret_cast<bf16x4*>(&As[(srow + i * 32) * 40 + scol]) = a4;
      *reinterpret_cast<bf16x4*>(&Bs[(srow + i * 32) * 40 + scol]) = b4;
    }
    __syncthreads();

    bf16x8 a[4], b[4];
#pragma unroll
    for (int m = 0; m < 4; ++m)
      a[m] = *reinterpret_cast<const bf16x8*>(&As[(wm + m * 16 + lr) * 40 + lk]);
#pragma unroll
    for (int n = 0; n < 4; ++n)
      b[n] = *reinterpret_cast<const bf16x8*>(&Bs[(wn + n * 16 + lr) * 40 + lk]);
#pragma unroll
    for (int m = 0; m < 4; ++m)
#pragma unroll
      for (int n = 0; n < 4; ++n)
        acc[m][n] = __builtin_amdgcn_mfma_f32_16x16x32_bf16(a[m], b[n], acc[m][n], 0, 0, 0);
  }
  __syncthreads();

  const size_t imOff = (size_t)M_DIM * OUTF;
  int fq = (lane >> 4) * 4;
#pragma unroll
  for (int m = 0; m < 4; ++m) {
    int gr = bm * 128 + wm + m * 16 + fq;
#pragma unroll
    for (int n = 0; n < 4; ++n) {
      int gc = bn * 128 + wn + n * 16 + lr;
      float* dst = (gc < OUTF) ? (out + (size_t)gr * OUTF + gc)
                               : (out + imOff + (size_t)gr * OUTF + (gc - OUTF));
#pragma unroll
      for (int j = 0; j < 4; ++j)
        dst[(size_t)j * OUTF] = acc[m][n][j];
    }
  }
}

// ---------------------------------------------------------------------------
extern "C" void kernel_launch(void* const* d_in, const int* in_sizes, int n_in,
                              void* d_out, int out_size, void* d_ws, size_t ws_size,
                              hipStream_t stream) {
  const float* xre = (const float*)d_in[0];
  const float* xim = (const float*)d_in[1];
  const float* wre = (const float*)d_in[2];
  const float* wim = (const float*)d_in[3];
  float* out = (float*)d_out;

  const size_t need = (size_t)2 * 4096 * 4096 * sizeof(bf16_t);  // 64 MiB
  if (ws_size >= need) {
    bf16_t* Abf = (bf16_t*)d_ws;
    bf16_t* Bbf = Abf + (size_t)4096 * 4096;
    hipLaunchKernelGGL(pack_ab, dim3(16384), dim3(256), 0, stream,
                       xre, xim, wre, wim, Abf, Bbf);
    hipLaunchKernelGGL(gemm256_bd, dim3(256), dim3(512), 0, stream,
                       Abf, Bbf, out);
  } else {
    hipLaunchKernelGGL(gemm_fused, dim3(1024), dim3(256), 0, stream,
                       xre, xim, wre, wim, out);
  }
}

// Round 10
// 145.089 us; speedup vs baseline: 1.3561x; 1.3561x over previous
//
#include <hip/hip_runtime.h>

typedef __bf16 bf16_t;
typedef __bf16 bf16x8 __attribute__((ext_vector_type(8)));
typedef __bf16 bf16x4 __attribute__((ext_vector_type(4)));
typedef float f32x4 __attribute__((ext_vector_type(4)));

#define M_DIM 4096
#define N_DIM 4096   // 2 * OUT_FEATURES
#define K_DIM 4096   // 2 * IN_FEATURES
#define OUTF 2048
#define INF 2048
#define LDK 4096
#define NT 64        // K-tiles of 64

// ---------------------------------------------------------------------------
// Pack kernel: build bf16 A = [x_re | x_im]  (4096 x 4096)
//              and  bf16 B = [[w_re, -w_im]; [w_im, w_re]] (4096 x 4096)
// ---------------------------------------------------------------------------
__global__ __launch_bounds__(256) void pack_ab(
    const float* __restrict__ xre, const float* __restrict__ xim,
    const float* __restrict__ wre, const float* __restrict__ wim,
    bf16_t* __restrict__ Abf, bf16_t* __restrict__ Bbf)
{
  size_t gid = (size_t)blockIdx.x * 256 + threadIdx.x;
  size_t e8  = gid * 8;
  const size_t MAT = (size_t)4096 * 4096;
  bool isB = e8 >= MAT;
  size_t e = isB ? (e8 - MAT) : e8;
  int row = (int)(e >> 12);
  int k   = (int)(e & 4095);

  const float* src;
  float s = 1.0f;
  if (!isB) {
    src = (k < INF) ? (xre + (size_t)row * INF + k)
                    : (xim + (size_t)row * INF + (k - INF));
  } else {
    if (row < OUTF) {
      if (k < INF) { src = wre + (size_t)row * INF + k; }
      else         { src = wim + (size_t)row * INF + (k - INF); s = -1.0f; }
    } else {
      int o = row - OUTF;
      src = (k < INF) ? (wim + (size_t)o * INF + k)
                      : (wre + (size_t)o * INF + (k - INF));
    }
  }
  const float4* p = reinterpret_cast<const float4*>(src);
  float4 f0 = p[0];
  float4 f1 = p[1];
  bf16x8 v;
  v[0] = (bf16_t)(f0.x * s); v[1] = (bf16_t)(f0.y * s);
  v[2] = (bf16_t)(f0.z * s); v[3] = (bf16_t)(f0.w * s);
  v[4] = (bf16_t)(f1.x * s); v[5] = (bf16_t)(f1.y * s);
  v[6] = (bf16_t)(f1.z * s); v[7] = (bf16_t)(f1.w * s);
  bf16_t* dst = (isB ? Bbf : Abf) + e;
  *reinterpret_cast<bf16x8*>(dst) = v;
}

// ---------------------------------------------------------------------------
__device__ __forceinline__ void gld_lds16(const void* g, void* l) {
  __builtin_amdgcn_global_load_lds(
      (const __attribute__((address_space(1))) void*)g,
      (__attribute__((address_space(3))) void*)l,
      16, 0, 0);
}

// ---------------------------------------------------------------------------
// 256x256 GEMM, balanced 6/6/6/6 read schedule (R10).
//   Model (fits R3-R8 data): phase time = max(LDS drain, MFMA). R3's read
//   distribution 12/4/8/0 -> 1152+621+768+621 = 4400cyc/tile (measured).
//   Balanced 6 reads/phase -> 576 < 621 MFMA -> every phase MFMA-bound.
//   Reads: P1 b1+a1[0] | P2 a1[1..3] | P3 next a0'[0..2] (c^1) | P4(post-QB)
//   a0'[3]+b0' (c^1). lgkm FIFO-counted: 6 / 8 / 6. Quadrant order
//   QA(0,0) QD(0,1) QC(1,1) QB(1,0).
//   Staging 1 HT/phase (m201 cadence): P1 t+1.B1->c^1; P2 t+2.A0->c;
//   P3 t+2.B0->c; P4 t+2.A1->c. vmcnt(4)+BAR at P2-end (t+1 A/B halves
//   resident before P3/P4 cross-tile reads, >=3-phase cover each);
//   vmcnt(6)+BAR at boundary (drains only t+1.B1, 3-phase cover).
//   Swizzle (R3-verified, conflicts==0):
//     phys_kbyte = logical_kbyte ^ ((row&3)<<4) ^ (((row>>2)&1)<<6)
// ---------------------------------------------------------------------------

template<int QM, int QN>
__device__ __forceinline__ void mfma_quad(f32x4 (&acc)[8][4],
                                          const bf16x8 (&aF)[4][2],
                                          const bf16x8 (&bF)[2][2]) {
  __builtin_amdgcn_s_setprio(1);
#pragma unroll
  for (int m = 0; m < 4; ++m)
#pragma unroll
    for (int n = 0; n < 2; ++n) {
      f32x4 v = acc[QM * 4 + m][QN * 2 + n];
      v = __builtin_amdgcn_mfma_f32_16x16x32_bf16(aF[m][0], bF[n][0], v, 0, 0, 0);
      v = __builtin_amdgcn_mfma_f32_16x16x32_bf16(aF[m][1], bF[n][1], v, 0, 0, 0);
      acc[QM * 4 + m][QN * 2 + n] = v;
    }
  __builtin_amdgcn_s_setprio(0);
}

__global__ __launch_bounds__(512, 2) void gemm256(
    const bf16_t* __restrict__ A, const bf16_t* __restrict__ B,
    float* __restrict__ out)
{
  // LDS: buf c at c*65536 B; within buf: A-half0|A-half1|B-half0|B-half1,
  // each half = 128 rows x 64 cols bf16 = 16384 B (row stride 128 B).
  __shared__ alignas(16) bf16_t lds[2 * 32768];
  char* Lb = (char*)lds;

  const int tid  = threadIdx.x;
  const int lane = tid & 63;
  const int wid  = tid >> 6;
  const int wm   = wid >> 2;   // 0..1  -> rows wm*128..+127  (A-half wm)
  const int wn   = wid & 3;    // 0..3  -> cols wn*64..+63
  const int lr   = lane & 15;
  const int kg   = (lane >> 4) * 16;                         // logical slot
  const int xm   = ((lr & 3) << 4) | (((lr >> 2) & 1) << 6); // row-XOR mask

  int bid = blockIdx.x;
  int swz = (bid & 7) * 32 + (bid >> 3);   // XCD-aware, 256 blocks % 8 == 0
  const int bm = swz >> 4;                  // 0..15
  const int bn = swz & 15;                  // 0..15

  // Staging source precompute: physical P = j*8192 + tid*16 within a half;
  // row = P>>7, p = P&127; logical kbyte = p ^ ((row&3)<<4) ^ ((row>>2&1)<<6)
  int rS[2], kS[2];
#pragma unroll
  for (int j = 0; j < 2; ++j) {
    int P   = j * 8192 + tid * 16;
    int row = P >> 7;
    int p   = P & 127;
    int L   = p ^ ((row & 3) << 4) ^ (((row >> 2) & 1) << 6);
    rS[j] = row;
    kS[j] = L >> 1;           // k element (0..63)
  }
  const bf16_t* As0 = A + (size_t)(bm * 256 + rS[0]) * LDK + kS[0];
  const bf16_t* As1 = A + (size_t)(bm * 256 + rS[1]) * LDK + kS[1];
  const bf16_t* Bs0 = B + (size_t)(bn * 256 + rS[0]) * LDK + kS[0];
  const bf16_t* Bs1 = B + (size_t)(bn * 256 + rS[1]) * LDK + kS[1];
  const int dst16 = tid * 16;

#define STAGE_A(t, h, c) do {                                                  \
    gld_lds16(As0 + (size_t)(h) * 128 * LDK + (t) * 64,                        \
              Lb + (c) * 65536 + (h) * 16384 + dst16);                         \
    gld_lds16(As1 + (size_t)(h) * 128 * LDK + (t) * 64,                        \
              Lb + (c) * 65536 + (h) * 16384 + 8192 + dst16);                  \
  } while (0)
#define STAGE_B(t, h, c) do {                                                  \
    gld_lds16(Bs0 + (size_t)(h) * 128 * LDK + (t) * 64,                        \
              Lb + (c) * 65536 + 32768 + (h) * 16384 + dst16);                 \
    gld_lds16(Bs1 + (size_t)(h) * 128 * LDK + (t) * 64,                        \
              Lb + (c) * 65536 + 32768 + (h) * 16384 + 8192 + dst16);          \
  } while (0)
// A frag: row-in-half = qm*64+m*16+lr (half = wm); swizzled kbyte
#define RD_A(c, qm, m, ks)                                                     \
  (*(const bf16x8*)(Lb + (c) * 65536 + wm * 16384 +                            \
                    ((qm) * 64 + (m) * 16 + lr) * 128 +                        \
                    ((((ks) * 64) | kg) ^ xm)))
// B frag: row = wn*64+qn*32+n*16+lr -> half wn>>1, row-in-half rest
#define RD_B(c, qn, n, ks)                                                     \
  (*(const bf16x8*)(Lb + (c) * 65536 + 32768 + (wn >> 1) * 16384 +             \
                    ((wn & 1) * 64 + (qn) * 32 + (n) * 16 + lr) * 128 +        \
                    ((((ks) * 64) | kg) ^ xm)))
#define BAR()   __builtin_amdgcn_s_barrier()
#define SB()    __builtin_amdgcn_sched_barrier(0)

  f32x4 acc[8][4];
#pragma unroll
  for (int i = 0; i < 8; ++i)
#pragma unroll
    for (int j = 0; j < 4; ++j)
      acc[i][j] = (f32x4){0.f, 0.f, 0.f, 0.f};

  bf16x8 a0[4][2], b0[2][2];   // loop-carried Q1 frags of the CURRENT tile

  // Prologue: t0 full (8 loads) + t1.A0,B0,A1 (6 loads; B1 staged at t0 P1).
  // vmcnt(6): t0 resident, t1 trio in flight (= steady-state entry).
  STAGE_A(0, 0, 0); STAGE_A(0, 1, 0);
  STAGE_B(0, 0, 0); STAGE_B(0, 1, 0);
  STAGE_A(1, 0, 1); STAGE_B(1, 0, 1); STAGE_A(1, 1, 1);
  asm volatile("s_waitcnt vmcnt(6)" ::: "memory");
  BAR();
  // carried reads for t0 (12): the "P3/P4 of t-1" issues
#pragma unroll
  for (int m = 0; m < 4; ++m) { a0[m][0] = RD_A(0, 0, m, 0); a0[m][1] = RD_A(0, 0, m, 1); }
#pragma unroll
  for (int n = 0; n < 2; ++n) { b0[n][0] = RD_B(0, 0, n, 0); b0[n][1] = RD_B(0, 0, n, 1); }
  SB();

  for (int t = 0; t < NT; ++t) {
    const int c = t & 1;
    bf16x8 a1[4][2], b1[2][2];

    // ---- P1: stage t+1.B1 -> c^1; reads b1(4)+a1[0](2); lgkm(6) covers
    // the 12 carried reads; QA.
    if (t + 1 < NT) STAGE_B(t + 1, 1, c ^ 1);
#pragma unroll
    for (int n = 0; n < 2; ++n) { b1[n][0] = RD_B(c, 1, n, 0); b1[n][1] = RD_B(c, 1, n, 1); }
    a1[0][0] = RD_A(c, 1, 0, 0); a1[0][1] = RD_A(c, 1, 0, 1);
    SB(); BAR();
    asm volatile("s_waitcnt lgkmcnt(6)" ::: "memory");
    SB();
    mfma_quad<0, 0>(acc, a0, b0);                    // QA: a0 x b0

    // ---- P2: stage t+2.A0 -> c; reads a1[1..3](6); lgkm(8) covers b1; QD.
    // Then vmcnt(4)+BAR: t+1's A0,B0,A1 globally resident (staged >=3
    // phases ago) before P3/P4's cross-tile reads of buf c^1.
    if (t + 2 < NT) STAGE_A(t + 2, 0, c);
#pragma unroll
    for (int m = 1; m < 4; ++m) { a1[m][0] = RD_A(c, 1, m, 0); a1[m][1] = RD_A(c, 1, m, 1); }
    SB(); BAR();
    asm volatile("s_waitcnt lgkmcnt(8)" ::: "memory");
    SB();
    mfma_quad<0, 1>(acc, a0, b1);                    // QD: a0 x b1 (a0 last use)
    if (t + 1 < NT) {
      if (t + 2 < NT) asm volatile("s_waitcnt vmcnt(4)" ::: "memory");
      else            asm volatile("s_waitcnt vmcnt(2)" ::: "memory");
      BAR();
    }

    // ---- P3: stage t+2.B0 -> c; reads next-tile a0'[0..2] (6, buf c^1);
    // lgkm(6) covers a1; QC.
    if (t + 2 < NT) STAGE_B(t + 2, 0, c);
    if (t + 1 < NT) {
#pragma unroll
      for (int m = 0; m < 3; ++m) {
        a0[m][0] = RD_A(c ^ 1, 0, m, 0); a0[m][1] = RD_A(c ^ 1, 0, m, 1);
      }
      SB(); BAR();
      asm volatile("s_waitcnt lgkmcnt(6)" ::: "memory");
    } else {
      SB(); BAR();
      asm volatile("s_waitcnt lgkmcnt(0)" ::: "memory");
    }
    SB();
    mfma_quad<1, 1>(acc, a1, b1);                    // QC: a1 x b1 (b1 last use)

    // ---- P4: stage t+2.A1 -> c; QB (b0 last use); THEN issue a0'[3]+b0'
    // (avoids WAR on b0); boundary vmcnt(6)+BAR drains t+1.B1 only.
    if (t + 2 < NT) STAGE_A(t + 2, 1, c);
    SB();
    mfma_quad<1, 0>(acc, a1, b0);                    // QB: a1 x b0
    SB();
    if (t + 1 < NT) {
      a0[3][0] = RD_A(c ^ 1, 0, 3, 0); a0[3][1] = RD_A(c ^ 1, 0, 3, 1);
#pragma unroll
      for (int n = 0; n < 2; ++n) {
        b0[n][0] = RD_B(c ^ 1, 0, n, 0); b0[n][1] = RD_B(c ^ 1, 0, n, 1);
      }
      SB();
    }
    if (t + 2 < NT)      asm volatile("s_waitcnt vmcnt(6)" ::: "memory");
    else if (t + 1 < NT) asm volatile("s_waitcnt vmcnt(0)" ::: "memory");
    BAR();
  }

  // Epilogue: C/D layout col=lane&15, row=(lane>>4)*4+j (verified m89/m91)
  const size_t imOff = (size_t)M_DIM * OUTF;
  const int fq = (lane >> 4) * 4;
  const bool isIm = (bn * 256) >= OUTF;          // bn>=8 -> imaginary half
  float* obase = out + (isIm ? imOff : 0);
  const int colBase = bn * 256 - (isIm ? OUTF : 0) + wn * 64;
#pragma unroll
  for (int ar = 0; ar < 8; ++ar) {
    int gr = bm * 256 + wm * 128 + ar * 16 + fq;
#pragma unroll
    for (int cc = 0; cc < 4; ++cc) {
      int gc = colBase + cc * 16 + lr;
#pragma unroll
      for (int j = 0; j < 4; ++j)
        obase[(size_t)(gr + j) * OUTF + gc] = acc[ar][cc][j];
    }
  }
#undef STAGE_A
#undef STAGE_B
#undef RD_A
#undef RD_B
#undef BAR
#undef SB
}

// ---------------------------------------------------------------------------
// Fallback: fused fp32->bf16 conversion + GEMM (no workspace needed).
// ---------------------------------------------------------------------------
__global__ __launch_bounds__(256) void gemm_fused(
    const float* __restrict__ xre, const float* __restrict__ xim,
    const float* __restrict__ wre, const float* __restrict__ wim,
    float* __restrict__ out)
{
  __shared__ alignas(16) bf16_t As[128 * 40];
  __shared__ alignas(16) bf16_t Bs[128 * 40];

  int tid = threadIdx.x;
  int bid = blockIdx.x;
  int swz = (bid & 7) * 128 + (bid >> 3);
  int bm = swz >> 5;
  int bn = swz & 31;

  int lane = tid & 63;
  int w    = tid >> 6;
  int wm   = (w >> 1) * 64;
  int wn   = (w & 1) * 64;
  int lr   = lane & 15;
  int lk   = (lane >> 4) * 8;

  f32x4 acc[4][4];
#pragma unroll
  for (int m = 0; m < 4; ++m)
#pragma unroll
    for (int n = 0; n < 4; ++n)
      acc[m][n] = (f32x4){0.f, 0.f, 0.f, 0.f};

  int srow = tid >> 3;
  int scol = (tid & 7) * 4;

  bool nIm  = (bn * 128) >= OUTF;
  int nbase = nIm ? (bn * 128 - OUTF) : (bn * 128);

  for (int kt = 0; kt < K_DIM / 32; ++kt) {
    int k0 = kt * 32;
    bool kHi = (k0 >= INF);
    int kk = kHi ? (k0 - INF) : k0;

    const float* Asrc = (kHi ? xim : xre) + (size_t)(bm * 128) * INF + kk;
    const float* Bsrc;
    float s = 1.0f;
    if (!nIm) { if (!kHi) { Bsrc = wre; } else { Bsrc = wim; s = -1.0f; } }
    else      { Bsrc = kHi ? wre : wim; }
    Bsrc += (size_t)nbase * INF + kk;

    float4 av[4], bv[4];
#pragma unroll
    for (int i = 0; i < 4; ++i) {
      av[i] = *reinterpret_cast<const float4*>(Asrc + (size_t)(srow + i * 32) * INF + scol);
      bv[i] = *reinterpret_cast<const float4*>(Bsrc + (size_t)(srow + i * 32) * INF + scol);
    }
    __syncthreads();
#pragma unroll
    for (int i = 0; i < 4; ++i) {
      bf16x4 a4, b4;
      a4[0] = (bf16_t)av[i].x; a4[1] = (bf16_t)av[i].y;
      a4[2] = (bf16_t)av[i].z; a4[3] = (bf16_t)av[i].w;
      b4[0] = (bf16_t)(bv[i].x * s); b4[1] = (bf16_t)(bv[i].y * s);
      b4[2] = (bf16_t)(bv[i].z * s); b4[3] = (bf16_t)(bv[i].w * s);
      *reinterpret_cast<bf16x4*>(&As[(srow + i * 32) * 40 + scol]) = a4;
      *reinterpret_cast<bf16x4*>(&Bs[(srow + i * 32) * 40 + scol]) = b4;
    }
    __syncthreads();

    bf16x8 a[4], b[4];
#pragma unroll
    for (int m = 0; m < 4; ++m)
      a[m] = *reinterpret_cast<const bf16x8*>(&As[(wm + m * 16 + lr) * 40 + lk]);
#pragma unroll
    for (int n = 0; n < 4; ++n)
      b[n] = *reinterpret_cast<const bf16x8*>(&Bs[(wn + n * 16 + lr) * 40 + lk]);
#pragma unroll
    for (int m = 0; m < 4; ++m)
#pragma unroll
      for (int n = 0; n < 4; ++n)
        acc[m][n] = __builtin_amdgcn_mfma_f32_16x16x32_bf16(a[m], b[n], acc[m][n], 0, 0, 0);
  }
  __syncthreads();

  const size_t imOff = (size_t)M_DIM * OUTF;
  int fq = (lane >> 4) * 4;
#pragma unroll
  for (int m = 0; m < 4; ++m) {
    int gr = bm * 128 + wm + m * 16 + fq;
#pragma unroll
    for (int n = 0; n < 4; ++n) {
      int gc = bn * 128 + wn + n * 16 + lr;
      float* dst = (gc < OUTF) ? (out + (size_t)gr * OUTF + gc)
                               : (out + imOff + (size_t)gr * OUTF + (gc - OUTF));
#pragma unroll
      for (int j = 0; j < 4; ++j)
        dst[(size_t)j * OUTF] = acc[m][n][j];
    }
  }
}

// ---------------------------------------------------------------------------
extern "C" void kernel_launch(void* const* d_in, const int* in_sizes, int n_in,
                              void* d_out, int out_size, void* d_ws, size_t ws_size,
                              hipStream_t stream) {
  const float* xre = (const float*)d_in[0];
  const float* xim = (const float*)d_in[1];
  const float* wre = (const float*)d_in[2];
  const float* wim = (const float*)d_in[3];
  float* out = (float*)d_out;

  const size_t need = (size_t)2 * 4096 * 4096 * sizeof(bf16_t);  // 64 MiB
  if (ws_size >= need) {
    bf16_t* Abf = (bf16_t*)d_ws;
    bf16_t* Bbf = Abf + (size_t)4096 * 4096;
    hipLaunchKernelGGL(pack_ab, dim3(16384), dim3(256), 0, stream,
                       xre, xim, wre, wim, Abf, Bbf);
    hipLaunchKernelGGL(gemm256, dim3(256), dim3(512), 0, stream,
                       Abf, Bbf, out);
  } else {
    hipLaunchKernelGGL(gemm_fused, dim3(1024), dim3(256), 0, stream,
                       xre, xim, wre, wim, out);
  }
}